// Round 1
// 1067.203 us; speedup vs baseline: 1.0171x; 1.0171x over previous
//
#include <hip/hip_runtime.h>
#include <cstdint>
#include <cstddef>

#define N_NODES 65536
#define E_EDGES 65535
#define DIN     512
#define KDIM    1024
#define JDIM    1024
#define HEADS   4
#define DOUT    256

typedef short   short8  __attribute__((ext_vector_type(8)));
typedef float   floatx4 __attribute__((ext_vector_type(4)));

__device__ inline float bf2f(unsigned short u){
  union { unsigned int i; float f; } c; c.i = ((unsigned int)u) << 16; return c.f;
}
__device__ inline unsigned short f2bf(float f){
  union { float f; unsigned int i; } c; c.f = f;
  unsigned int r = c.i + 0x7FFFu + ((c.i >> 16) & 1u);
  return (unsigned short)(r >> 16);
}
// map float -> uint with same ordering (ascending)
__device__ inline unsigned int okey(float f){
  union { float f; unsigned int u; } c; c.f = f;
  return (c.u & 0x80000000u) ? ~c.u : (c.u | 0x80000000u);
}
__device__ inline float unokey(unsigned int k){
  union { unsigned int u; float f; } c;
  c.u = (k & 0x80000000u) ? (k ^ 0x80000000u) : ~k;
  return c.f;
}
__device__ inline float leaky(float x){ return x >= 0.f ? x : 0.2f * x; }
__device__ inline float gelu_f(float x){
  return 0.5f * x * (1.f + tanhf(0.7978845608028654f * (x + 0.044715f * x * x * x)));
}

// ---------------- score + bf16 cast ----------------
__global__ void k_prep(const float* __restrict__ x, const float* __restrict__ sr,
                       const float* __restrict__ nmask, const float* __restrict__ sw,
                       const float* __restrict__ sb, unsigned short* __restrict__ xs,
                       float* __restrict__ score){
  int i = blockIdx.x, t = threadIdx.x;
  float4 v;
  if (t < 128) v = *(const float4*)(x  + (size_t)i*DIN + 4*t);
  else         v = *(const float4*)(sr + (size_t)i*DIN + 4*(t-128));
  const float4 w = *(const float4*)(sw + 4*t);  // global col == 4*t in both halves
  double part = (double)v.x*(double)w.x + (double)v.y*(double)w.y
              + (double)v.z*(double)w.z + (double)v.w*(double)w.w;
  ushort4 o; o.x = f2bf(v.x); o.y = f2bf(v.y); o.z = f2bf(v.z); o.w = f2bf(v.w);
  *(ushort4*)(xs + (size_t)i*KDIM + 4*t) = o;
  for (int sdel = 32; sdel; sdel >>= 1) part += __shfl_down(part, sdel);
  __shared__ double red[4];
  if ((t & 63) == 0) red[t >> 6] = part;
  __syncthreads();
  if (t == 0){
    double s = red[0] + red[1] + red[2] + red[3] + (double)sb[0];
    score[i] = (float)s * nmask[i];
  }
}

__global__ void k_nnz(const float* __restrict__ score, int* scal){
  int i = blockIdx.x*256 + threadIdx.x;
  int nz = (score[i] != 0.f) ? 1 : 0;
  unsigned long long b = __ballot(nz);
  if ((threadIdx.x & 63) == 0) atomicAdd(&scal[0], (int)__popcll(b));
}

__global__ void k_makekey(const float* __restrict__ score, unsigned int* __restrict__ key){
  int i = blockIdx.x*256 + threadIdx.x;
  float v = score[i];
  if (v == 0.f) v = __builtin_inff();   // masked = inf
  key[i] = okey(v);
}

// scal: [0]=nnz [1]=prune [2]=k [3]=prefix/Kstar [4]=rank/need [5]=eqcnt
__global__ void k_initsel(int* scal){
  int nnz = scal[0];
  double prod = (double)nnz * 0.3;        // IEEE-identical to Python
  scal[1] = ((int)prod != 0) ? 1 : 0;
  int k = (int)(prod + 1.0);
  scal[2] = k; scal[3] = 0; scal[4] = k;
}

__global__ void k_hist(const unsigned int* __restrict__ key, unsigned int* __restrict__ hist,
                       const int* __restrict__ scal, int pass){
  __shared__ unsigned int lh[256];
  int t = threadIdx.x;
  lh[t] = 0; __syncthreads();
  int i = blockIdx.x*256 + t;
  unsigned int kv = key[i];
  unsigned int pref = (unsigned int)scal[3];
  bool ok = (pass == 0) || ((kv >> (32 - 8*pass)) == pref);
  if (ok) atomicAdd(&lh[(kv >> (24 - 8*pass)) & 255u], 1u);
  __syncthreads();
  if (lh[t]) atomicAdd(&hist[t], lh[t]);
}

__global__ void k_select(unsigned int* __restrict__ hist, int* __restrict__ scal){
  __shared__ unsigned int h[256];
  int t = threadIdx.x;
  h[t] = hist[t];
  __syncthreads();
  if (t == 0){
    unsigned int r = (unsigned int)scal[4];
    unsigned int cum = 0, pref = (unsigned int)scal[3];
    for (int b = 0; b < 256; b++){
      unsigned int c = h[b];
      if (cum + c >= r){
        scal[3] = (int)((pref << 8) | (unsigned int)b);
        scal[4] = (int)(r - cum);
        break;
      }
      cum += c;
    }
  }
  __syncthreads();
  hist[t] = 0;  // ready for next pass
}

__global__ void k_mark(const unsigned int* __restrict__ key, int* __restrict__ scal,
                       int* __restrict__ rem, int* __restrict__ eqlist){
  if (!scal[1]) return;
  int i = blockIdx.x*256 + threadIdx.x;
  unsigned int Ks = (unsigned int)scal[3];
  unsigned int kv = key[i];
  if (kv < Ks) rem[i] = 1;
  else if (kv == Ks){
    int p = atomicAdd(&scal[5], 1);
    if (p < 4096) eqlist[p] = i;
  }
}

__global__ void k_ties(int* __restrict__ scal, int* __restrict__ eqlist, int* __restrict__ rem){
  if (!scal[1]) return;
  int m = scal[5]; if (m > 4096) m = 4096;
  int need = scal[4]; if (need > m) need = m;
  for (int it = 0; it < need; it++){          // lowest indices first (top_k tie rule)
    int best = 0x7FFFFFFF, bj = -1;
    for (int j = 0; j < m; j++){ int v = eqlist[j]; if (v < best){ best = v; bj = j; } }
    if (bj < 0) break;
    rem[best] = 1; eqlist[bj] = 0x7FFFFFFF;
  }
}

// one of 5 parent-climb iterations (rem[0]==0 guaranteed)
__global__ void k_remap(const int* __restrict__ pin, const int* __restrict__ rem,
                        int* __restrict__ pout){
  int e = blockIdx.x*256 + threadIdx.x;
  if (e >= E_EDGES) return;
  int p = pin[e];
  pout[e] = rem[p] ? (p == 0 ? 0 : pin[p-1]) : p;
}

// masked edges (child removed) are ALL (0,0) with alpha == node0 self-loop alpha;
// exclude them (dstF=-1) and account analytically with weight k on node 0.
__global__ void k_edges(const int* __restrict__ srcIn, const int* __restrict__ pfin,
                        const int* __restrict__ rem, int* __restrict__ srcF,
                        int* __restrict__ dstF, int* __restrict__ cnt){
  int e = blockIdx.x*256 + threadIdx.x;
  if (e >= E_EDGES) return;
  int s = srcIn[e];
  if (rem[s]){ srcF[e] = 0; dstF[e] = -1; }
  else {
    srcF[e] = s;
    int d = pfin[e];
    dstF[e] = d;
    atomicAdd(&cnt[d], 1);
  }
}

__global__ void k_scan1(const int* __restrict__ cnt, int* __restrict__ offs,
                        int* __restrict__ bsum){
  int b = blockIdx.x, t = threadIdx.x, i = b*256 + t;
  int v = cnt[i];
  int lane = t & 63, wv = t >> 6;
  int xv = v;
  for (int o2 = 1; o2 < 64; o2 <<= 1){ int y = __shfl_up(xv, o2); if (lane >= o2) xv += y; }
  __shared__ int wt_[4];
  if (lane == 63) wt_[wv] = xv;
  __syncthreads();
  int add = 0;
  for (int k2 = 0; k2 < wv; k2++) add += wt_[k2];
  offs[i] = xv + add - v;
  if (t == 255) bsum[b] = xv + add;
}

__global__ void k_scan2(int* __restrict__ bsum){
  int t = threadIdx.x;
  int v = bsum[t];
  int lane = t & 63, wv = t >> 6;
  int xv = v;
  for (int o2 = 1; o2 < 64; o2 <<= 1){ int y = __shfl_up(xv, o2); if (lane >= o2) xv += y; }
  __shared__ int wt_[4];
  if (lane == 63) wt_[wv] = xv;
  __syncthreads();
  int add = 0;
  for (int k2 = 0; k2 < wv; k2++) add += wt_[k2];
  bsum[t] = xv + add - v;  // exclusive
}

__global__ void k_scan3(int* __restrict__ offs, const int* __restrict__ bsum,
                        int* __restrict__ cur){
  int b = blockIdx.x, t = threadIdx.x, i = b*256 + t;
  int v = offs[i] + bsum[b];
  offs[i] = v; cur[i] = v;
}

__global__ void k_fill(const int* __restrict__ dstF, int* __restrict__ cur,
                       int* __restrict__ elist){
  int e = blockIdx.x*256 + threadIdx.x;
  if (e >= E_EDGES) return;
  int d = dstF[e]; if (d < 0) return;
  int pos = atomicAdd(&cur[d], 1);
  elist[pos] = e;
}

// gat_w[0:1024][:] -> bf16 transposed (wt[j][k] = gat_w[k][j])
__global__ void k_wt(const float* __restrict__ gw, unsigned short* __restrict__ wtb){
  __shared__ float tile[32][33];
  int kt = blockIdx.x*32, jt = blockIdx.y*32;
  int tx = threadIdx.x, ty = threadIdx.y;    // (32,8)
  for (int r = ty; r < 32; r += 8) tile[r][tx] = gw[(size_t)(kt+r)*JDIM + jt + tx];
  __syncthreads();
  for (int r = ty; r < 32; r += 8) wtb[(size_t)(jt+r)*KDIM + kt + tx] = f2bf(tile[tx][r]);
}

// tc[t][j] = sum_c gelu(emb_w[t][c]+emb_b[c]) * gat_w[1024+c][j]  (2 distinct type rows)
__global__ void k_tc(const float* __restrict__ embw, const float* __restrict__ embb,
                     const float* __restrict__ gw, float* __restrict__ tc){
  int g = blockIdx.x*256 + threadIdx.x;   // 0..2047
  int te = g >> 10, j = g & 1023;
  float acc = 0.f;
  for (int c = 0; c < DOUT; c++){
    float e = gelu_f(embw[te*DOUT + c] + embb[c]);
    acc += e * gw[(size_t)(KDIM + c)*JDIM + j];
  }
  tc[te*JDIM + j] = acc;
}

// 256x256-tile, BK=64, 8-wave, double-buffered 2-phase bf16 MFMA GEMM:
//   h = xs @ W (+ tc[type]) -> bf16
// Pipeline per K-tile: STAGE(next tile into other buffer) || COMPUTE(current),
// then ONE __syncthreads (its implicit vmcnt(0)+lgkmcnt(0) is the drain).
#define BKG 64
__global__ __launch_bounds__(512, 2) void k_gemm(const unsigned short* __restrict__ xs,
    const unsigned short* __restrict__ wtb, const float* __restrict__ tc,
    const int* __restrict__ tid, unsigned short* __restrict__ hmat){
  __shared__ unsigned short As[2][256*BKG];   // 32 KB per buffer
  __shared__ unsigned short Bs[2][256*BKG];   // total 128 KB LDS
  int bid = blockIdx.x;
  // bijective XCD swizzle (1024 blocks, 1024%8==0): the 4 jb-blocks sharing an
  // A-panel land on consecutive slots of one XCD -> A fetched from HBM once.
  int xcd = bid & 7, tq = bid >> 3;
  int jb = tq & 3, ip = (tq >> 2)*8 + xcd;     // ip in 0..255, jb in 0..3
  int rowbase = ip*256, colbase = jb*256;
  int t = threadIdx.x, wave = t >> 6, lane = t & 63;
  int wm = (wave >> 2)*128, wn = (wave & 3)*64;   // 2x4 wave grid, 128x64 per wave
  floatx4 acc[8][4];
  floatx4 zero = {0.f, 0.f, 0.f, 0.f};
  #pragma unroll
  for (int a = 0; a < 8; a++)
    #pragma unroll
    for (int b = 0; b < 4; b++) acc[a][b] = zero;

  // staging geometry: per round r (0..3), wave w stages chunk ci=r*8+w
  // = rows [ci*8, ci*8+8) x 64 cols; lane l covers LDS bytes ci*1024 + l*16
  // (lane-contiguous as global_load_lds requires).
  int srow = lane >> 3;        // 0..7 row within chunk
  int scol = (lane & 7)*8;     // element col offset (8 bf16 = 16 B)

  auto STAGE = [&](int buf, int kt){
    int k0 = kt*BKG;
    #pragma unroll
    for (int r = 0; r < 4; r++){
      int ci = r*8 + wave;
      int row = ci*8 + srow;
      const unsigned short* ga = xs  + (size_t)(rowbase + row)*KDIM + k0 + scol;
      __builtin_amdgcn_global_load_lds((const __attribute__((address_space(1))) void*)ga,
          (__attribute__((address_space(3))) void*)(&As[buf][ci*512 + lane*8]), 16, 0, 0);
      const unsigned short* gb = wtb + (size_t)(colbase + row)*KDIM + k0 + scol;
      __builtin_amdgcn_global_load_lds((const __attribute__((address_space(1))) void*)gb,
          (__attribute__((address_space(3))) void*)(&Bs[buf][ci*512 + lane*8]), 16, 0, 0);
    }
  };

  int rr = lane & 15, rq = (lane >> 4)*8;
  auto COMPUTE = [&](int buf){
    #pragma unroll
    for (int ks = 0; ks < 2; ks++){
      short8 af[8], bfr[4];
      #pragma unroll
      for (int mi = 0; mi < 8; mi++)
        af[mi]  = *(const short8*)(&As[buf][(wm + mi*16 + rr)*BKG + ks*32 + rq]);
      #pragma unroll
      for (int ni = 0; ni < 4; ni++)
        bfr[ni] = *(const short8*)(&Bs[buf][(wn + ni*16 + rr)*BKG + ks*32 + rq]);
      #pragma unroll
      for (int mi = 0; mi < 8; mi++)
        #pragma unroll
        for (int ni = 0; ni < 4; ni++)
          acc[mi][ni] = __builtin_amdgcn_mfma_f32_16x16x32_bf16(af[mi], bfr[ni], acc[mi][ni], 0, 0, 0);
    }
  };

  const int NT = KDIM / BKG;   // 16 K-tiles
  STAGE(0, 0);
  __syncthreads();             // implicit vmcnt(0) drain: tile 0 ready
  int cur = 0;
  for (int kt = 0; kt < NT - 1; kt++){
    STAGE(cur ^ 1, kt + 1);    // issue next-tile loads BEFORE compute
    COMPUTE(cur);              // MFMA on current tile hides the staging
    __syncthreads();           // one barrier/tile: drains vmcnt, next tile ready
    cur ^= 1;
  }
  COMPUTE(cur);                // epilogue tile (no prefetch)

  int q = lane >> 4, cc = lane & 15;
  #pragma unroll
  for (int mi = 0; mi < 8; mi++){
    #pragma unroll
    for (int reg = 0; reg < 4; reg++){
      int rowg = rowbase + wm + mi*16 + q*4 + reg;
      int tt = tid[rowg];
      #pragma unroll
      for (int ni = 0; ni < 4; ni++){
        int col = colbase + wn + ni*16 + cc;
        float v = acc[mi][ni][reg] + tc[tt*JDIM + col];
        hmat[(size_t)rowg*JDIM + col] = f2bf(v);
      }
    }
  }
}

__global__ void k_att(const unsigned short* __restrict__ hmat, const float* __restrict__ atts,
                      const float* __restrict__ attd, float* __restrict__ asrc,
                      float* __restrict__ adst){
  int i = blockIdx.x, t = threadIdx.x;
  int hd = t >> 6, c = (t & 63)*4;
  ushort4 hv = *(const ushort4*)(hmat + (size_t)i*JDIM + hd*DOUT + c);
  float h0 = bf2f(hv.x), h1 = bf2f(hv.y), h2 = bf2f(hv.z), h3 = bf2f(hv.w);
  float4 ws_ = *(const float4*)(atts + hd*DOUT + c);
  float4 wd_ = *(const float4*)(attd + hd*DOUT + c);
  float ps = h0*ws_.x + h1*ws_.y + h2*ws_.z + h3*ws_.w;
  float pd = h0*wd_.x + h1*wd_.y + h2*wd_.z + h3*wd_.w;
  for (int sdel = 32; sdel; sdel >>= 1){ ps += __shfl_down(ps, sdel); pd += __shfl_down(pd, sdel); }
  if ((t & 63) == 0){ asrc[i*HEADS + hd] = ps; adst[i*HEADS + hd] = pd; }
}

__global__ void k_max(const int* __restrict__ srcF, const int* __restrict__ dstF,
                      const float* __restrict__ asrc, const float* __restrict__ adst,
                      unsigned int* __restrict__ mkey){
  int idx = blockIdx.x*256 + threadIdx.x;
  if (idx >= E_EDGES + N_NODES) return;
  int s, d;
  if (idx < E_EDGES){ d = dstF[idx]; if (d < 0) return; s = srcF[idx]; }
  else { s = d = idx - E_EDGES; }
  for (int hd = 0; hd < HEADS; hd++){
    float al = leaky(asrc[s*HEADS + hd] + adst[d*HEADS + hd]);
    atomicMax(&mkey[d*HEADS + hd], okey(al));
  }
}

__global__ void k_sum(const int* __restrict__ srcF, const int* __restrict__ dstF,
                      const float* __restrict__ asrc, const float* __restrict__ adst,
                      const unsigned int* __restrict__ mkey, float* __restrict__ ssum,
                      const int* __restrict__ scal){
  int idx = blockIdx.x*256 + threadIdx.x;
  if (idx >= E_EDGES + N_NODES) return;
  int s, d; float wgt = 1.f;
  if (idx < E_EDGES){ d = dstF[idx]; if (d < 0) return; s = srcF[idx]; }
  else {
    s = d = idx - E_EDGES;
    if (d == 0 && scal[1]) wgt = 1.f + (float)scal[2];   // k masked (0,0) copies + self
  }
  for (int hd = 0; hd < HEADS; hd++){
    float al = leaky(asrc[s*HEADS + hd] + adst[d*HEADS + hd]);
    float e = expf(al - unokey(mkey[d*HEADS + hd]));
    atomicAdd(&ssum[d*HEADS + hd], wgt * e);
  }
}

__global__ void k_agg(const unsigned short* __restrict__ hmat, const int* __restrict__ srcF,
                      const float* __restrict__ asrc, const float* __restrict__ adst,
                      const unsigned int* __restrict__ mkey, const float* __restrict__ ssum,
                      const int* __restrict__ offs, const int* __restrict__ cnt,
                      const int* __restrict__ elist, const float* __restrict__ gatb,
                      const int* __restrict__ scal, float* __restrict__ out){
  int n = blockIdx.x, t = threadIdx.x;
  int hd = t >> 6;                     // 4*t in [hd*256,(hd+1)*256)
  float mh = unokey(mkey[n*HEADS + hd]);
  float sh = ssum[n*HEADS + hd] + 1e-16f;
  float adn = adst[n*HEADS + hd];
  float a0 = 0.f, a1 = 0.f, a2 = 0.f, a3 = 0.f;
  { // self-loop (+ k masked copies on node 0)
    float al = leaky(asrc[n*HEADS + hd] + adn);
    float coef = expf(al - mh) / sh;
    if (n == 0 && scal[1]) coef *= (1.f + (float)scal[2]);
    ushort4 hv = *(const ushort4*)(hmat + (size_t)n*JDIM + 4*t);
    a0 += coef*bf2f(hv.x); a1 += coef*bf2f(hv.y); a2 += coef*bf2f(hv.z); a3 += coef*bf2f(hv.w);
  }
  int o0 = offs[n], c_ = cnt[n];
  for (int q2 = 0; q2 < c_; q2++){
    int e = elist[o0 + q2];
    int s = srcF[e];
    float al = leaky(asrc[s*HEADS + hd] + adn);
    float coef = expf(al - mh) / sh;
    ushort4 hv = *(const ushort4*)(hmat + (size_t)s*JDIM + 4*t);
    a0 += coef*bf2f(hv.x); a1 += coef*bf2f(hv.y); a2 += coef*bf2f(hv.z); a3 += coef*bf2f(hv.w);
  }
  const float4 gb = *(const float4*)(gatb + 4*t);
  float4 ov;
  ov.x = gelu_f(a0 + gb.x); ov.y = gelu_f(a1 + gb.y);
  ov.z = gelu_f(a2 + gb.z); ov.w = gelu_f(a3 + gb.w);
  *(float4*)(out + (size_t)n*JDIM + 4*t) = ov;
}

__global__ void k_nm(const float* __restrict__ nmask, const int* __restrict__ rem,
                     float* __restrict__ nmout){
  int i = blockIdx.x*256 + threadIdx.x;
  float u = (i == 0) ? 1.f : (1.f - (float)rem[i]);
  nmout[i] = nmask[i] * u;
}

extern "C" void kernel_launch(void* const* d_in, const int* in_sizes, int n_in,
                              void* d_out, int out_size, void* d_ws, size_t ws_size,
                              hipStream_t stream){
  (void)in_sizes; (void)n_in; (void)out_size; (void)ws_size;
  const float* x    = (const float*)d_in[0];
  const int*  eidx  = (const int*)d_in[1];
  const float* sr   = (const float*)d_in[3];
  const float* nmask= (const float*)d_in[4];
  const int*  tid   = (const int*)d_in[5];
  const float* sw   = (const float*)d_in[6];
  const float* sb   = (const float*)d_in[7];
  const float* embw = (const float*)d_in[8];
  const float* embb = (const float*)d_in[9];
  const float* gw   = (const float*)d_in[10];
  const float* atts = (const float*)d_in[11];
  const float* attd = (const float*)d_in[12];
  const float* gatb = (const float*)d_in[13];
  float* out = (float*)d_out;

  char* w = (char*)d_ws;
  size_t o = 0;
  auto alloc = [&](size_t bytes){ size_t r = o; o += (bytes + 255) & ~(size_t)255; return r; };
  // zeroed region (single memset)
  size_t o_cnt  = alloc((size_t)N_NODES*4);
  size_t o_mkey = alloc((size_t)N_NODES*HEADS*4);
  size_t o_ssum = alloc((size_t)N_NODES*HEADS*4);
  size_t o_rem  = alloc((size_t)N_NODES*4);
  size_t o_hist = alloc(256*4);
  size_t o_scal = alloc(64);
  size_t o_eq   = alloc(4096*4);
  size_t zero_bytes = o;
  // not zeroed
  size_t o_score= alloc((size_t)N_NODES*4);
  size_t o_key  = alloc((size_t)N_NODES*4);
  size_t o_pA   = alloc((size_t)E_EDGES*4);
  size_t o_pB   = alloc((size_t)E_EDGES*4);
  size_t o_srcF = alloc((size_t)E_EDGES*4);
  size_t o_dstF = alloc((size_t)E_EDGES*4);
  size_t o_off  = alloc((size_t)N_NODES*4);
  size_t o_cur  = alloc((size_t)N_NODES*4);
  size_t o_el   = alloc((size_t)E_EDGES*4);
  size_t o_bsum = alloc(256*4);
  size_t o_asrc = alloc((size_t)N_NODES*HEADS*4);
  size_t o_adst = alloc((size_t)N_NODES*HEADS*4);
  size_t o_tc   = alloc((size_t)2*JDIM*4);
  size_t o_wt   = alloc((size_t)JDIM*KDIM*2);
  size_t o_xs   = alloc((size_t)N_NODES*KDIM*2);
  size_t o_h    = alloc((size_t)N_NODES*JDIM*2);

  int* cnt   = (int*)(w + o_cnt);
  unsigned int* mkey = (unsigned int*)(w + o_mkey);
  float* ssum = (float*)(w + o_ssum);
  int* rem   = (int*)(w + o_rem);
  unsigned int* hist = (unsigned int*)(w + o_hist);
  int* scal  = (int*)(w + o_scal);
  int* eqlist= (int*)(w + o_eq);
  float* score = (float*)(w + o_score);
  unsigned int* key = (unsigned int*)(w + o_key);
  int* pA = (int*)(w + o_pA);
  int* pB = (int*)(w + o_pB);
  int* srcF = (int*)(w + o_srcF);
  int* dstF = (int*)(w + o_dstF);
  int* offs = (int*)(w + o_off);
  int* cur  = (int*)(w + o_cur);
  int* elist= (int*)(w + o_el);
  int* bsum = (int*)(w + o_bsum);
  float* asrc = (float*)(w + o_asrc);
  float* adst = (float*)(w + o_adst);
  float* tc = (float*)(w + o_tc);
  unsigned short* wtb = (unsigned short*)(w + o_wt);
  unsigned short* xs  = (unsigned short*)(w + o_xs);
  unsigned short* hmat= (unsigned short*)(w + o_h);

  hipMemsetAsync(w, 0, zero_bytes, stream);

  k_prep<<<N_NODES, 256, 0, stream>>>(x, sr, nmask, sw, sb, xs, score);
  k_nnz<<<N_NODES/256, 256, 0, stream>>>(score, scal);
  k_makekey<<<N_NODES/256, 256, 0, stream>>>(score, key);
  k_initsel<<<1, 1, 0, stream>>>(scal);
  for (int p = 0; p < 4; p++){
    k_hist<<<N_NODES/256, 256, 0, stream>>>(key, hist, scal, p);
    k_select<<<1, 256, 0, stream>>>(hist, scal);
  }
  k_mark<<<N_NODES/256, 256, 0, stream>>>(key, scal, rem, eqlist);
  k_ties<<<1, 1, 0, stream>>>(scal, eqlist, rem);

  const int* par_in = eidx + E_EDGES;   // edge_index row 1
  int egrid = (E_EDGES + 255)/256;
  k_remap<<<egrid, 256, 0, stream>>>(par_in, rem, pA);
  k_remap<<<egrid, 256, 0, stream>>>(pA, rem, pB);
  k_remap<<<egrid, 256, 0, stream>>>(pB, rem, pA);
  k_remap<<<egrid, 256, 0, stream>>>(pA, rem, pB);
  k_remap<<<egrid, 256, 0, stream>>>(pB, rem, pA);

  k_edges<<<egrid, 256, 0, stream>>>(eidx, pA, rem, srcF, dstF, cnt);
  k_scan1<<<256, 256, 0, stream>>>(cnt, offs, bsum);
  k_scan2<<<1, 256, 0, stream>>>(bsum);
  k_scan3<<<256, 256, 0, stream>>>(offs, bsum, cur);
  k_fill<<<egrid, 256, 0, stream>>>(dstF, cur, elist);

  k_wt<<<dim3(32,32), dim3(32,8), 0, stream>>>(gw, wtb);
  k_tc<<<8, 256, 0, stream>>>(embw, embb, gw, tc);
  k_gemm<<<1024, 512, 0, stream>>>(xs, wtb, tc, tid, hmat);
  k_att<<<N_NODES, 256, 0, stream>>>(hmat, atts, attd, asrc, adst);

  int mg = (E_EDGES + N_NODES + 255)/256;
  k_max<<<mg, 256, 0, stream>>>(srcF, dstF, asrc, adst, mkey);
  k_sum<<<mg, 256, 0, stream>>>(srcF, dstF, asrc, adst, mkey, ssum, scal);
  k_agg<<<N_NODES, 256, 0, stream>>>(hmat, srcF, asrc, adst, mkey, ssum, offs, cnt,
                                     elist, gatb, scal, out);
  k_nm<<<N_NODES/256, 256, 0, stream>>>(nmask, rem, out + (size_t)N_NODES*JDIM);
}

// Round 2
// 976.935 us; speedup vs baseline: 1.1111x; 1.0924x over previous
//
#include <hip/hip_runtime.h>
#include <cstdint>
#include <cstddef>

#define N_NODES 65536
#define E_EDGES 65535
#define DIN     512
#define KDIM    1024
#define JDIM    1024
#define HEADS   4
#define DOUT    256

typedef short   short8  __attribute__((ext_vector_type(8)));
typedef unsigned short ushort8 __attribute__((ext_vector_type(8)));
typedef float   floatx4 __attribute__((ext_vector_type(4)));

__device__ inline float bf2f(unsigned short u){
  union { unsigned int i; float f; } c; c.i = ((unsigned int)u) << 16; return c.f;
}
__device__ inline unsigned short f2bf(float f){
  union { float f; unsigned int i; } c; c.f = f;
  unsigned int r = c.i + 0x7FFFu + ((c.i >> 16) & 1u);
  return (unsigned short)(r >> 16);
}
// map float -> uint with same ordering (ascending)
__device__ inline unsigned int okey(float f){
  union { float f; unsigned int u; } c; c.f = f;
  return (c.u & 0x80000000u) ? ~c.u : (c.u | 0x80000000u);
}
__device__ inline float unokey(unsigned int k){
  union { unsigned int u; float f; } c;
  c.u = (k & 0x80000000u) ? (k ^ 0x80000000u) : ~k;
  return c.f;
}
__device__ inline float leaky(float x){ return x >= 0.f ? x : 0.2f * x; }
__device__ inline float gelu_f(float x){
  return 0.5f * x * (1.f + tanhf(0.7978845608028654f * (x + 0.044715f * x * x * x)));
}

// ---------------- score + bf16 cast + key (wave-per-row) ----------------
__global__ void k_prep(const float* __restrict__ x, const float* __restrict__ sr,
                       const float* __restrict__ nmask, const float* __restrict__ sw,
                       const float* __restrict__ sb, unsigned short* __restrict__ xs,
                       float* __restrict__ score, unsigned int* __restrict__ key){
  int lane = threadIdx.x & 63, wv = threadIdx.x >> 6;
  int i = blockIdx.x*4 + wv;
  const float* xr  = x  + (size_t)i*DIN + 8*lane;
  const float* srr = sr + (size_t)i*DIN + 8*lane;
  float4 a0 = *(const float4*)(xr);
  float4 a1 = *(const float4*)(xr + 4);
  float4 b0 = *(const float4*)(srr);
  float4 b1 = *(const float4*)(srr + 4);
  float4 w0 = *(const float4*)(sw + 8*lane);
  float4 w1 = *(const float4*)(sw + 8*lane + 4);
  float4 w2 = *(const float4*)(sw + 512 + 8*lane);
  float4 w3 = *(const float4*)(sw + 512 + 8*lane + 4);
  double part = (double)a0.x*(double)w0.x + (double)a0.y*(double)w0.y
              + (double)a0.z*(double)w0.z + (double)a0.w*(double)w0.w
              + (double)a1.x*(double)w1.x + (double)a1.y*(double)w1.y
              + (double)a1.z*(double)w1.z + (double)a1.w*(double)w1.w
              + (double)b0.x*(double)w2.x + (double)b0.y*(double)w2.y
              + (double)b0.z*(double)w2.z + (double)b0.w*(double)w2.w
              + (double)b1.x*(double)w3.x + (double)b1.y*(double)w3.y
              + (double)b1.z*(double)w3.z + (double)b1.w*(double)w3.w;
  ushort8 oa, ob;
  oa[0]=f2bf(a0.x); oa[1]=f2bf(a0.y); oa[2]=f2bf(a0.z); oa[3]=f2bf(a0.w);
  oa[4]=f2bf(a1.x); oa[5]=f2bf(a1.y); oa[6]=f2bf(a1.z); oa[7]=f2bf(a1.w);
  ob[0]=f2bf(b0.x); ob[1]=f2bf(b0.y); ob[2]=f2bf(b0.z); ob[3]=f2bf(b0.w);
  ob[4]=f2bf(b1.x); ob[5]=f2bf(b1.y); ob[6]=f2bf(b1.z); ob[7]=f2bf(b1.w);
  *(ushort8*)(xs + (size_t)i*KDIM + 8*lane)       = oa;
  *(ushort8*)(xs + (size_t)i*KDIM + 512 + 8*lane) = ob;
  for (int sdel = 32; sdel; sdel >>= 1) part += __shfl_down(part, sdel);
  if (lane == 0){
    float fs = (float)(part + (double)sb[0]);
    float s  = fs * nmask[i];
    score[i] = s;
    float v = (s == 0.f) ? __builtin_inff() : s;
    key[i] = okey(v);
  }
}

__global__ void k_nnz(const float* __restrict__ score, int* scal){
  int i = blockIdx.x*256 + threadIdx.x;
  int nz = (score[i] != 0.f) ? 1 : 0;
  unsigned long long b = __ballot(nz);
  if ((threadIdx.x & 63) == 0) atomicAdd(&scal[0], (int)__popcll(b));
}

// scal: [0]=nnz [1]=prune [2]=k [3]=prefix/Kstar [4]=rank/need [5]=eqcnt
__global__ void k_initsel(int* scal){
  int nnz = scal[0];
  double prod = (double)nnz * 0.3;        // IEEE-identical to Python
  scal[1] = ((int)prod != 0) ? 1 : 0;
  int k = (int)(prod + 1.0);
  scal[2] = k; scal[3] = 0; scal[4] = k;
}

__global__ void k_hist(const unsigned int* __restrict__ key, unsigned int* __restrict__ hist,
                       const int* __restrict__ scal, int pass){
  __shared__ unsigned int lh[256];
  int t = threadIdx.x;
  lh[t] = 0; __syncthreads();
  int i = blockIdx.x*256 + t;
  unsigned int kv = key[i];
  unsigned int pref = (unsigned int)scal[3];
  bool ok = (pass == 0) || ((kv >> (32 - 8*pass)) == pref);
  if (ok) atomicAdd(&lh[(kv >> (24 - 8*pass)) & 255u], 1u);
  __syncthreads();
  if (lh[t]) atomicAdd(&hist[t], lh[t]);
}

__global__ void k_select(unsigned int* __restrict__ hist, int* __restrict__ scal){
  __shared__ unsigned int h[256];
  int t = threadIdx.x;
  h[t] = hist[t];
  __syncthreads();
  if (t == 0){
    unsigned int r = (unsigned int)scal[4];
    unsigned int cum = 0, pref = (unsigned int)scal[3];
    for (int b = 0; b < 256; b++){
      unsigned int c = h[b];
      if (cum + c >= r){
        scal[3] = (int)((pref << 8) | (unsigned int)b);
        scal[4] = (int)(r - cum);
        break;
      }
      cum += c;
    }
  }
  __syncthreads();
  hist[t] = 0;  // ready for next pass
}

__global__ void k_mark(const unsigned int* __restrict__ key, int* __restrict__ scal,
                       int* __restrict__ rem, int* __restrict__ eqlist){
  if (!scal[1]) return;
  int i = blockIdx.x*256 + threadIdx.x;
  unsigned int Ks = (unsigned int)scal[3];
  unsigned int kv = key[i];
  if (kv < Ks) rem[i] = 1;
  else if (kv == Ks){
    int p = atomicAdd(&scal[5], 1);
    if (p < 4096) eqlist[p] = i;
  }
}

__global__ void k_ties(int* __restrict__ scal, int* __restrict__ eqlist, int* __restrict__ rem){
  if (!scal[1]) return;
  int m = scal[5]; if (m > 4096) m = 4096;
  int need = scal[4]; if (need > m) need = m;
  for (int it = 0; it < need; it++){          // lowest indices first (top_k tie rule)
    int best = 0x7FFFFFFF, bj = -1;
    for (int j = 0; j < m; j++){ int v = eqlist[j]; if (v < best){ best = v; bj = j; } }
    if (bj < 0) break;
    rem[best] = 1; eqlist[bj] = 0x7FFFFFFF;
  }
}

// one of 5 parent-climb iterations (rem[0]==0 guaranteed)
__global__ void k_remap(const int* __restrict__ pin, const int* __restrict__ rem,
                        int* __restrict__ pout){
  int e = blockIdx.x*256 + threadIdx.x;
  if (e >= E_EDGES) return;
  int p = pin[e];
  pout[e] = rem[p] ? (p == 0 ? 0 : pin[p-1]) : p;
}

// masked edges (child removed) are ALL (0,0) with alpha == node0 self-loop alpha;
// exclude them (dstF=-1) and account analytically with weight k on node 0.
__global__ void k_edges(const int* __restrict__ srcIn, const int* __restrict__ pfin,
                        const int* __restrict__ rem, int* __restrict__ srcF,
                        int* __restrict__ dstF, int* __restrict__ cnt){
  int e = blockIdx.x*256 + threadIdx.x;
  if (e >= E_EDGES) return;
  int s = srcIn[e];
  if (rem[s]){ srcF[e] = 0; dstF[e] = -1; }
  else {
    srcF[e] = s;
    int d = pfin[e];
    dstF[e] = d;
    atomicAdd(&cnt[d], 1);
  }
}

__global__ void k_scan1(const int* __restrict__ cnt, int* __restrict__ offs,
                        int* __restrict__ bsum){
  int b = blockIdx.x, t = threadIdx.x, i = b*256 + t;
  int v = cnt[i];
  int lane = t & 63, wv = t >> 6;
  int xv = v;
  for (int o2 = 1; o2 < 64; o2 <<= 1){ int y = __shfl_up(xv, o2); if (lane >= o2) xv += y; }
  __shared__ int wt_[4];
  if (lane == 63) wt_[wv] = xv;
  __syncthreads();
  int add = 0;
  for (int k2 = 0; k2 < wv; k2++) add += wt_[k2];
  offs[i] = xv + add - v;
  if (t == 255) bsum[b] = xv + add;
}

__global__ void k_scan2(int* __restrict__ bsum){
  int t = threadIdx.x;
  int v = bsum[t];
  int lane = t & 63, wv = t >> 6;
  int xv = v;
  for (int o2 = 1; o2 < 64; o2 <<= 1){ int y = __shfl_up(xv, o2); if (lane >= o2) xv += y; }
  __shared__ int wt_[4];
  if (lane == 63) wt_[wv] = xv;
  __syncthreads();
  int add = 0;
  for (int k2 = 0; k2 < wv; k2++) add += wt_[k2];
  bsum[t] = xv + add - v;  // exclusive
}

__global__ void k_scan3(int* __restrict__ offs, const int* __restrict__ bsum,
                        int* __restrict__ cur){
  int b = blockIdx.x, t = threadIdx.x, i = b*256 + t;
  int v = offs[i] + bsum[b];
  offs[i] = v; cur[i] = v;
}

__global__ void k_fill(const int* __restrict__ dstF, int* __restrict__ cur,
                       int* __restrict__ elist){
  int e = blockIdx.x*256 + threadIdx.x;
  if (e >= E_EDGES) return;
  int d = dstF[e]; if (d < 0) return;
  int pos = atomicAdd(&cur[d], 1);
  elist[pos] = e;
}

// gat_w[0:1024][:] -> bf16 transposed (wt[j][k] = gat_w[k][j])
__global__ void k_wt(const float* __restrict__ gw, unsigned short* __restrict__ wtb){
  __shared__ float tile[32][33];
  int kt = blockIdx.x*32, jt = blockIdx.y*32;
  int tx = threadIdx.x, ty = threadIdx.y;    // (32,8)
  for (int r = ty; r < 32; r += 8) tile[r][tx] = gw[(size_t)(kt+r)*JDIM + jt + tx];
  __syncthreads();
  for (int r = ty; r < 32; r += 8) wtb[(size_t)(jt+r)*KDIM + kt + tx] = f2bf(tile[tx][r]);
}

// tc[t][j] = sum_c gelu(emb_w[t][c]+emb_b[c]) * gat_w[1024+c][j]  (2 distinct type rows)
// gelu hoisted to LDS (was: 256 tanhf per thread)
__global__ void k_tc(const float* __restrict__ embw, const float* __restrict__ embb,
                     const float* __restrict__ gw, float* __restrict__ tc){
  __shared__ float eg[2][DOUT];
  int t = threadIdx.x;
  eg[0][t] = gelu_f(embw[t] + embb[t]);
  eg[1][t] = gelu_f(embw[DOUT + t] + embb[t]);
  __syncthreads();
  int g = blockIdx.x*256 + t;   // 0..2047
  int te = g >> 10, j = g & 1023;
  float acc = 0.f;
  #pragma unroll 8
  for (int c = 0; c < DOUT; c++){
    acc += eg[te][c] * gw[(size_t)(KDIM + c)*JDIM + j];
  }
  tc[te*JDIM + j] = acc;
}

// 256x256-tile, BK=64, 8-wave, double-buffered 2-phase bf16 MFMA GEMM:
//   h = xs @ W (+ tc[type]) -> bf16;  FUSED: per-head att dots (block's 256 cols
//   == exactly head jb's DOUT segment, so a_src/a_dst complete in-block).
#define BKG 64
__global__ __launch_bounds__(512, 2) void k_gemm(const unsigned short* __restrict__ xs,
    const unsigned short* __restrict__ wtb, const float* __restrict__ tc,
    const int* __restrict__ tid, const float* __restrict__ atts,
    const float* __restrict__ attd, unsigned short* __restrict__ hmat,
    float* __restrict__ asrc, float* __restrict__ adst){
  __shared__ unsigned short As[2][256*BKG];   // 32 KB per buffer
  __shared__ unsigned short Bs[2][256*BKG];   // total 128 KB LDS
  int bid = blockIdx.x;
  // bijective XCD swizzle (1024 blocks, 1024%8==0): the 4 jb-blocks sharing an
  // A-panel land on consecutive slots of one XCD -> A fetched from HBM once.
  int xcd = bid & 7, tq = bid >> 3;
  int jb = tq & 3, ip = (tq >> 2)*8 + xcd;     // ip in 0..255, jb in 0..3
  int rowbase = ip*256, colbase = jb*256;
  int t = threadIdx.x, wave = t >> 6, lane = t & 63;
  int wm = (wave >> 2)*128, wn = (wave & 3)*64;   // 2x4 wave grid, 128x64 per wave
  floatx4 acc[8][4];
  floatx4 zero = {0.f, 0.f, 0.f, 0.f};
  #pragma unroll
  for (int a = 0; a < 8; a++)
    #pragma unroll
    for (int b = 0; b < 4; b++) acc[a][b] = zero;

  // staging geometry: per round r (0..3), wave w stages chunk ci=r*8+w
  // = rows [ci*8, ci*8+8) x 64 cols; lane l covers LDS bytes ci*1024 + l*16
  // (lane-contiguous as global_load_lds requires).
  int srow = lane >> 3;        // 0..7 row within chunk
  int scol = (lane & 7)*8;     // element col offset (8 bf16 = 16 B)

  auto STAGE = [&](int buf, int kt){
    int k0 = kt*BKG;
    #pragma unroll
    for (int r = 0; r < 4; r++){
      int ci = r*8 + wave;
      int row = ci*8 + srow;
      const unsigned short* ga = xs  + (size_t)(rowbase + row)*KDIM + k0 + scol;
      __builtin_amdgcn_global_load_lds((const __attribute__((address_space(1))) void*)ga,
          (__attribute__((address_space(3))) void*)(&As[buf][ci*512 + lane*8]), 16, 0, 0);
      const unsigned short* gb = wtb + (size_t)(colbase + row)*KDIM + k0 + scol;
      __builtin_amdgcn_global_load_lds((const __attribute__((address_space(1))) void*)gb,
          (__attribute__((address_space(3))) void*)(&Bs[buf][ci*512 + lane*8]), 16, 0, 0);
    }
  };

  int rr = lane & 15, rq = (lane >> 4)*8;
  auto COMPUTE = [&](int buf){
    #pragma unroll
    for (int ks = 0; ks < 2; ks++){
      short8 af[8], bfr[4];
      #pragma unroll
      for (int mi = 0; mi < 8; mi++)
        af[mi]  = *(const short8*)(&As[buf][(wm + mi*16 + rr)*BKG + ks*32 + rq]);
      #pragma unroll
      for (int ni = 0; ni < 4; ni++)
        bfr[ni] = *(const short8*)(&Bs[buf][(wn + ni*16 + rr)*BKG + ks*32 + rq]);
      #pragma unroll
      for (int mi = 0; mi < 8; mi++)
        #pragma unroll
        for (int ni = 0; ni < 4; ni++)
          acc[mi][ni] = __builtin_amdgcn_mfma_f32_16x16x32_bf16(af[mi], bfr[ni], acc[mi][ni], 0, 0, 0);
    }
  };

  const int NT = KDIM / BKG;   // 16 K-tiles
  STAGE(0, 0);
  __syncthreads();             // implicit vmcnt(0) drain: tile 0 ready
  int cur = 0;
  for (int kt = 0; kt < NT - 1; kt++){
    STAGE(cur ^ 1, kt + 1);    // issue next-tile loads BEFORE compute
    COMPUTE(cur);              // MFMA on current tile hides the staging
    __syncthreads();           // one barrier/tile: drains vmcnt, next tile ready
    cur ^= 1;
  }
  COMPUTE(cur);                // epilogue tile (no prefetch)

  // ---- epilogue: C-write + fused per-head att dots ----
  int q = lane >> 4, cc = lane & 15;
  float att_s[4], att_d[4];
  #pragma unroll
  for (int ni = 0; ni < 4; ni++){
    int cih = wn + ni*16 + cc;            // col within head jb
    att_s[ni] = atts[jb*DOUT + cih];
    att_d[ni] = attd[jb*DOUT + cih];
  }
  __syncthreads();                         // all LDS reads done -> reuse As
  float* sp = (float*)&As[0][0];           // [256 rows][4 wn-waves][2]
  #pragma unroll
  for (int mi = 0; mi < 8; mi++){
    #pragma unroll
    for (int reg = 0; reg < 4; reg++){
      int rloc = wm + mi*16 + q*4 + reg;
      int rowg = rowbase + rloc;
      int tt = tid[rowg];
      float ps = 0.f, pd = 0.f;
      #pragma unroll
      for (int ni = 0; ni < 4; ni++){
        int col = colbase + wn + ni*16 + cc;
        float v = acc[mi][ni][reg] + tc[tt*JDIM + col];
        hmat[(size_t)rowg*JDIM + col] = f2bf(v);
        ps += v * att_s[ni]; pd += v * att_d[ni];
      }
      #pragma unroll
      for (int m2 = 1; m2 < 16; m2 <<= 1){
        ps += __shfl_xor(ps, m2); pd += __shfl_xor(pd, m2);
      }
      if (cc == 0){
        sp[(rloc*4 + (wave & 3))*2 + 0] = ps;
        sp[(rloc*4 + (wave & 3))*2 + 1] = pd;
      }
    }
  }
  __syncthreads();
  if (t < 256){
    float s = 0.f, d2 = 0.f;
    #pragma unroll
    for (int w4 = 0; w4 < 4; w4++){ s += sp[(t*4 + w4)*2]; d2 += sp[(t*4 + w4)*2 + 1]; }
    asrc[(size_t)(rowbase + t)*HEADS + jb] = s;
    adst[(size_t)(rowbase + t)*HEADS + jb] = d2;
  }
}

__global__ void k_max(const int* __restrict__ srcF, const int* __restrict__ dstF,
                      const float* __restrict__ asrc, const float* __restrict__ adst,
                      unsigned int* __restrict__ mkey){
  int idx = blockIdx.x*256 + threadIdx.x;
  if (idx >= E_EDGES + N_NODES) return;
  int s, d;
  if (idx < E_EDGES){ d = dstF[idx]; if (d < 0) return; s = srcF[idx]; }
  else { s = d = idx - E_EDGES; }
  for (int hd = 0; hd < HEADS; hd++){
    float al = leaky(asrc[s*HEADS + hd] + adst[d*HEADS + hd]);
    atomicMax(&mkey[d*HEADS + hd], okey(al));
  }
}

__global__ void k_sum(const int* __restrict__ srcF, const int* __restrict__ dstF,
                      const float* __restrict__ asrc, const float* __restrict__ adst,
                      const unsigned int* __restrict__ mkey, float* __restrict__ ssum,
                      const int* __restrict__ scal){
  int idx = blockIdx.x*256 + threadIdx.x;
  if (idx >= E_EDGES + N_NODES) return;
  int s, d; float wgt = 1.f;
  if (idx < E_EDGES){ d = dstF[idx]; if (d < 0) return; s = srcF[idx]; }
  else {
    s = d = idx - E_EDGES;
    if (d == 0 && scal[1]) wgt = 1.f + (float)scal[2];   // k masked (0,0) copies + self
  }
  for (int hd = 0; hd < HEADS; hd++){
    float al = leaky(asrc[s*HEADS + hd] + adst[d*HEADS + hd]);
    float e = expf(al - unokey(mkey[d*HEADS + hd]));
    atomicAdd(&ssum[d*HEADS + hd], wgt * e);
  }
}

__global__ void k_agg(const unsigned short* __restrict__ hmat, const int* __restrict__ srcF,
                      const float* __restrict__ asrc, const float* __restrict__ adst,
                      const unsigned int* __restrict__ mkey, const float* __restrict__ ssum,
                      const int* __restrict__ offs, const int* __restrict__ cnt,
                      const int* __restrict__ elist, const float* __restrict__ gatb,
                      const int* __restrict__ scal, float* __restrict__ out){
  int n = blockIdx.x, t = threadIdx.x;
  int hd = t >> 6;                     // 4*t in [hd*256,(hd+1)*256)
  float mh = unokey(mkey[n*HEADS + hd]);
  float sh = ssum[n*HEADS + hd] + 1e-16f;
  float adn = adst[n*HEADS + hd];
  float a0 = 0.f, a1 = 0.f, a2 = 0.f, a3 = 0.f;
  { // self-loop (+ k masked copies on node 0)
    float al = leaky(asrc[n*HEADS + hd] + adn);
    float coef = expf(al - mh) / sh;
    if (n == 0 && scal[1]) coef *= (1.f + (float)scal[2]);
    ushort4 hv = *(const ushort4*)(hmat + (size_t)n*JDIM + 4*t);
    a0 += coef*bf2f(hv.x); a1 += coef*bf2f(hv.y); a2 += coef*bf2f(hv.z); a3 += coef*bf2f(hv.w);
  }
  int o0 = offs[n], c_ = cnt[n];
  for (int q2 = 0; q2 < c_; q2++){
    int e = elist[o0 + q2];
    int s = srcF[e];
    float al = leaky(asrc[s*HEADS + hd] + adn);
    float coef = expf(al - mh) / sh;
    ushort4 hv = *(const ushort4*)(hmat + (size_t)s*JDIM + 4*t);
    a0 += coef*bf2f(hv.x); a1 += coef*bf2f(hv.y); a2 += coef*bf2f(hv.z); a3 += coef*bf2f(hv.w);
  }
  const float4 gb = *(const float4*)(gatb + 4*t);
  float4 ov;
  ov.x = gelu_f(a0 + gb.x); ov.y = gelu_f(a1 + gb.y);
  ov.z = gelu_f(a2 + gb.z); ov.w = gelu_f(a3 + gb.w);
  *(float4*)(out + (size_t)n*JDIM + 4*t) = ov;
}

__global__ void k_nm(const float* __restrict__ nmask, const int* __restrict__ rem,
                     float* __restrict__ nmout){
  int i = blockIdx.x*256 + threadIdx.x;
  float u = (i == 0) ? 1.f : (1.f - (float)rem[i]);
  nmout[i] = nmask[i] * u;
}

extern "C" void kernel_launch(void* const* d_in, const int* in_sizes, int n_in,
                              void* d_out, int out_size, void* d_ws, size_t ws_size,
                              hipStream_t stream){
  (void)in_sizes; (void)n_in; (void)out_size; (void)ws_size;
  const float* x    = (const float*)d_in[0];
  const int*  eidx  = (const int*)d_in[1];
  const float* sr   = (const float*)d_in[3];
  const float* nmask= (const float*)d_in[4];
  const int*  tid   = (const int*)d_in[5];
  const float* sw   = (const float*)d_in[6];
  const float* sb   = (const float*)d_in[7];
  const float* embw = (const float*)d_in[8];
  const float* embb = (const float*)d_in[9];
  const float* gw   = (const float*)d_in[10];
  const float* atts = (const float*)d_in[11];
  const float* attd = (const float*)d_in[12];
  const float* gatb = (const float*)d_in[13];
  float* out = (float*)d_out;

  char* w = (char*)d_ws;
  size_t o = 0;
  auto alloc = [&](size_t bytes){ size_t r = o; o += (bytes + 255) & ~(size_t)255; return r; };
  // zeroed region (single memset)
  size_t o_cnt  = alloc((size_t)N_NODES*4);
  size_t o_mkey = alloc((size_t)N_NODES*HEADS*4);
  size_t o_ssum = alloc((size_t)N_NODES*HEADS*4);
  size_t o_rem  = alloc((size_t)N_NODES*4);
  size_t o_hist = alloc(256*4);
  size_t o_scal = alloc(64);
  size_t o_eq   = alloc(4096*4);
  size_t zero_bytes = o;
  // not zeroed
  size_t o_score= alloc((size_t)N_NODES*4);
  size_t o_key  = alloc((size_t)N_NODES*4);
  size_t o_pA   = alloc((size_t)E_EDGES*4);
  size_t o_pB   = alloc((size_t)E_EDGES*4);
  size_t o_srcF = alloc((size_t)E_EDGES*4);
  size_t o_dstF = alloc((size_t)E_EDGES*4);
  size_t o_off  = alloc((size_t)N_NODES*4);
  size_t o_cur  = alloc((size_t)N_NODES*4);
  size_t o_el   = alloc((size_t)E_EDGES*4);
  size_t o_bsum = alloc(256*4);
  size_t o_asrc = alloc((size_t)N_NODES*HEADS*4);
  size_t o_adst = alloc((size_t)N_NODES*HEADS*4);
  size_t o_tc   = alloc((size_t)2*JDIM*4);
  size_t o_wt   = alloc((size_t)JDIM*KDIM*2);
  size_t o_xs   = alloc((size_t)N_NODES*KDIM*2);
  size_t o_h    = alloc((size_t)N_NODES*JDIM*2);

  int* cnt   = (int*)(w + o_cnt);
  unsigned int* mkey = (unsigned int*)(w + o_mkey);
  float* ssum = (float*)(w + o_ssum);
  int* rem   = (int*)(w + o_rem);
  unsigned int* hist = (unsigned int*)(w + o_hist);
  int* scal  = (int*)(w + o_scal);
  int* eqlist= (int*)(w + o_eq);
  float* score = (float*)(w + o_score);
  unsigned int* key = (unsigned int*)(w + o_key);
  int* pA = (int*)(w + o_pA);
  int* pB = (int*)(w + o_pB);
  int* srcF = (int*)(w + o_srcF);
  int* dstF = (int*)(w + o_dstF);
  int* offs = (int*)(w + o_off);
  int* cur  = (int*)(w + o_cur);
  int* elist= (int*)(w + o_el);
  int* bsum = (int*)(w + o_bsum);
  float* asrc = (float*)(w + o_asrc);
  float* adst = (float*)(w + o_adst);
  float* tc = (float*)(w + o_tc);
  unsigned short* wtb = (unsigned short*)(w + o_wt);
  unsigned short* xs  = (unsigned short*)(w + o_xs);
  unsigned short* hmat= (unsigned short*)(w + o_h);

  hipMemsetAsync(w, 0, zero_bytes, stream);

  k_prep<<<N_NODES/4, 256, 0, stream>>>(x, sr, nmask, sw, sb, xs, score, key);
  k_nnz<<<N_NODES/256, 256, 0, stream>>>(score, scal);
  k_initsel<<<1, 1, 0, stream>>>(scal);
  for (int p = 0; p < 4; p++){
    k_hist<<<N_NODES/256, 256, 0, stream>>>(key, hist, scal, p);
    k_select<<<1, 256, 0, stream>>>(hist, scal);
  }
  k_mark<<<N_NODES/256, 256, 0, stream>>>(key, scal, rem, eqlist);
  k_ties<<<1, 1, 0, stream>>>(scal, eqlist, rem);

  const int* par_in = eidx + E_EDGES;   // edge_index row 1
  int egrid = (E_EDGES + 255)/256;
  k_remap<<<egrid, 256, 0, stream>>>(par_in, rem, pA);
  k_remap<<<egrid, 256, 0, stream>>>(pA, rem, pB);
  k_remap<<<egrid, 256, 0, stream>>>(pB, rem, pA);
  k_remap<<<egrid, 256, 0, stream>>>(pA, rem, pB);
  k_remap<<<egrid, 256, 0, stream>>>(pB, rem, pA);

  k_edges<<<egrid, 256, 0, stream>>>(eidx, pA, rem, srcF, dstF, cnt);
  k_scan1<<<256, 256, 0, stream>>>(cnt, offs, bsum);
  k_scan2<<<1, 256, 0, stream>>>(bsum);
  k_scan3<<<256, 256, 0, stream>>>(offs, bsum, cur);
  k_fill<<<egrid, 256, 0, stream>>>(dstF, cur, elist);

  k_wt<<<dim3(32,32), dim3(32,8), 0, stream>>>(gw, wtb);
  k_tc<<<8, 256, 0, stream>>>(embw, embb, gw, tc);
  k_gemm<<<1024, 512, 0, stream>>>(xs, wtb, tc, tid, atts, attd, hmat, asrc, adst);

  int mg = (E_EDGES + N_NODES + 255)/256;
  k_max<<<mg, 256, 0, stream>>>(srcF, dstF, asrc, adst, mkey);
  k_sum<<<mg, 256, 0, stream>>>(srcF, dstF, asrc, adst, mkey, ssum, scal);
  k_agg<<<N_NODES, 256, 0, stream>>>(hmat, srcF, asrc, adst, mkey, ssum, offs, cnt,
                                     elist, gatb, scal, out);
  k_nm<<<N_NODES/256, 256, 0, stream>>>(nmask, rem, out + (size_t)N_NODES*JDIM);
}